// Round 19
// baseline (1835.570 us; speedup 1.0000x reference)
//
#include <hip/hip_runtime.h>

// GNODecoder round 30: ABLATION ROUND (methodology: ablate before optimizing).
// r29 post-mortem: null (775 vs 763), confounded -- allocator spilled rr[8]
// to reach the 128-reg tier (WRITE 50->89MB). Six structural fixes all land
// 763-915us. Cycle accounting: VALU issue 203k cy/CU matches code; wall is
// 1.85M cy/CU -> waves stalled ~94% (~100k cy/wave for ~4k cy issue) at ~2
// blocks/CU. No nameable chain accounts for 10x -> measure, don't guess.
// r30 = r28 kernel (proven 763us, real output) + ONE diagnostic dispatch:
// SKEL variant keeps ALL memory ops (recs, 32 rndata gathers, weight
// staging, hb DS roundtrip, sacc atomics, agg tail) and strips all math
// (L0/gelu/MFMA), values kept live via atomics + asm sinks. Runs FIRST into
// agg; real kernel overwrites agg fully -> correctness preserved.
// Read: T_skel = total - 1167. >=600us -> memory-latency is the whole cost
// (next: f16 rndata 8->4MB L2-resident + XCD swizzle). <300us -> compute-
// side serialization (next: regs<=120 for 4 waves/SIMD).

#define BLOCK 256

typedef _Float16 half8 __attribute__((ext_vector_type(8)));
typedef float f32x4 __attribute__((ext_vector_type(4)));

// LDS byte layout (fused kernel):
//   [0,     8192)  W1T : [64 n][64 k] f16, chunk ^= (n&7)
//   [8192, 24576)  W2T : [128 n][64 k] f16, same swizzle
//   [24576, 32768) hbuf: per-wave 2 KB, [16 rows][8 chunks of 16B], chunk^=(row&7)
//   [32768, ... )  sacc: [QB][129] f32

__device__ __forceinline__ float gelu_f(float x) {
    // jax.nn.gelu default (approximate=True, tanh form)
    float x3 = x * x * x;
    float t  = 0.7978845608028654f * fmaf(0.044715f, x3, x);
    float e  = __expf(2.0f * t);
    float r  = __builtin_amdgcn_rcpf(e + 1.0f);
    return 0.5f * x * (1.0f + (1.0f - 2.0f * r));
}

// ---------- sort machinery (proven) ----------

__global__ void hist_kernel(const int* __restrict__ dst, int* __restrict__ hist, int E) {
    int e = blockIdx.x * blockDim.x + threadIdx.x;
    if (e < E) atomicAdd(&hist[dst[e]], 1);
}

__global__ __launch_bounds__(1024) void scan_kernel(const int* __restrict__ hist,
                                                    int* __restrict__ start, int n) {
    __shared__ int wsum[16];
    __shared__ int woff[16];
    int tid = threadIdx.x;
    int lane = tid & 63, wid = tid >> 6;
    int carry = 0;  // meaningful on tid 0 only
    for (int base = 0; base < n; base += 1024) {
        int i = base + tid;
        int v = (i < n) ? hist[i] : 0;
        int incl = v;
#pragma unroll
        for (int off = 1; off < 64; off <<= 1) {
            int t = __shfl_up(incl, off, 64);
            if (lane >= off) incl += t;
        }
        if (lane == 63) wsum[wid] = incl;
        __syncthreads();
        if (tid == 0) {
            int acc = carry;
#pragma unroll
            for (int w = 0; w < 16; ++w) { woff[w] = acc; acc += wsum[w]; }
            carry = acc;
        }
        __syncthreads();
        if (i < n) start[i] = woff[wid] + incl - v;
        __syncthreads();
    }
    if (threadIdx.x == 0) start[n] = carry;
}

// old path: positions only
__global__ void scatter_kernel(const int* __restrict__ dst, const int* __restrict__ src,
                               const int* __restrict__ start, int* __restrict__ cursor,
                               int* __restrict__ dsts, int* __restrict__ srcs, int E) {
    int e = blockIdx.x * blockDim.x + threadIdx.x;
    if (e >= E) return;
    int d = dst[e];
    int pos = start[d] + atomicAdd(&cursor[d], 1);
    dsts[pos] = d;
    srcs[pos] = src[e];
}

// rec path: 32B record {d, s, qpos[d].xyz, lpos[s].xyz}
__global__ void scatter_rec_kernel(const int* __restrict__ dst, const int* __restrict__ src,
                                   const int* __restrict__ start, int* __restrict__ cursor,
                                   const float* __restrict__ qpos,
                                   const float* __restrict__ lpos,
                                   uint4* __restrict__ recs, int E) {
    int e = blockIdx.x * blockDim.x + threadIdx.x;
    if (e >= E) return;
    int d = dst[e], s = src[e];
    int pos = start[d] + atomicAdd(&cursor[d], 1);
    const float* pq = qpos + (size_t)d * 3;
    const float* pl = lpos + (size_t)s * 3;
    uint4 u0, u1;
    u0.x = (unsigned)d;            u0.y = (unsigned)s;
    u0.z = __float_as_uint(pq[0]); u0.w = __float_as_uint(pq[1]);
    u1.x = __float_as_uint(pq[2]); u1.y = __float_as_uint(pl[0]);
    u1.z = __float_as_uint(pl[1]); u1.w = __float_as_uint(pl[2]);
    size_t ri = (size_t)pos * 2;
    recs[ri] = u0; recs[ri + 1] = u1;
}

// ---------- weight prep: f16, transposed [n][k], XOR-swizzled image ----------
// img bytes: W1T at [0,8192), W2T at [8192,24576).
// element (n,k): byte = base + n*128 + (((k>>3) ^ (n&7))*16) + (k&7)*2

__global__ void wprep_kernel(const float* __restrict__ W1,
                             const float* __restrict__ W2,
                             char* __restrict__ img) {
    union { _Float16 h[8]; uint4 u; } cv;
    for (int task = threadIdx.x; task < 1536; task += 256) {
        bool isW2 = task >= 512;
        int id = isW2 ? task - 512 : task;
        int n = id >> 3, kc = id & 7;
        const float* W = isW2 ? W2 : W1;
        int N = isW2 ? 128 : 64;
#pragma unroll
        for (int j = 0; j < 8; ++j) cv.h[j] = (_Float16)W[(kc * 8 + j) * N + n];
        *(uint4*)(img + (isW2 ? 8192 : 0) + n * 128 + ((kc ^ (n & 7)) * 16)) = cv.u;
    }
}

// ---------- fused: wave-private 16-edge tiles, zero barriers in loop ----------
// SKEL=true: memory skeleton -- all memory ops kept, all math stripped.

template <int QB, bool FUSED_PROJ, bool RECS, bool SKEL>
__global__ __launch_bounds__(BLOCK, 2) void fused_kernel(
    const float* __restrict__ rndata,   // [NL,128]
    const float* __restrict__ qpos,     // [NQ,3]
    const float* __restrict__ lpos,     // [NL,3]
    const uint4* __restrict__ recs,     // [E*2] edge records (RECS path)
    const int*   __restrict__ dsts,     // [E] sorted by dst (old path)
    const int*   __restrict__ srcs,     // [E] (old path)
    const int*   __restrict__ start,    // [NQ+1]
    const float* __restrict__ W0, const float* __restrict__ b0,
    const float* __restrict__ b1, const float* __restrict__ b2,
    const uint4* __restrict__ wimg,     // 24576 B packed W1T/W2T image
    const float* __restrict__ P0, const float* __restrict__ pb0,
    const float* __restrict__ P1, const float* __restrict__ pb1,
    float* __restrict__ agg,            // [NQ,128] mean (path A)
    float* __restrict__ out,            // [NQ,4]   (FUSED_PROJ)
    int nq)
{
    extern __shared__ char smemc[];
    float* sacc = (float*)(smemc + 32768);
    const int tid = threadIdx.x;

    // stage weight image -> LDS [0, 24576)
    {
        uint4* wdst = (uint4*)smemc;
        for (int i = tid; i < 1536; i += BLOCK) wdst[i] = wimg[i];
    }
    for (int i = tid; i < QB * 129; i += BLOCK) sacc[i] = 0.f;

    const int q0   = blockIdx.x * QB;
    const int qend = min(q0 + QB, nq);
    const int e0 = start[q0], e1 = start[qend];
    const int ntl = (e1 - e0 + 15) >> 4;   // 16-edge tiles

    const int m   = tid & 63;
    const int wid = tid >> 6;
    const int c16 = m & 15;
    const int g   = m >> 4;                // 0..3 = k-group

    char* hb = smemc + 24576 + wid * 2048; // wave-private h1 buffer
    const int aoff0 = c16 * 128 + (((0 + g) ^ (c16 & 7)) * 16);  // A frag k=g*8..
    const int aoff1 = c16 * 128 + (((4 + g) ^ (c16 & 7)) * 16);  // A frag k=32+g*8..

    // per-lane bias slices (hoisted; 12 loop-carried regs)
    float b1v[4], b2v[8];
#pragma unroll
    for (int nt = 0; nt < 4; ++nt) b1v[nt] = b1[nt * 16 + c16];
#pragma unroll
    for (int nt = 0; nt < 8; ++nt) b2v[nt] = b2[nt * 16 + c16];

    __syncthreads();  // weights staged + sacc zeroed (only barrier before tail)

    for (int t = wid; t < ntl; t += 4) {
        const int eb = e0 + (t << 4);

        float pin[6];
        int s_ep[4], soff[4];
        bool v_ep[4];

        if constexpr (RECS) {
            // ---- ONE coalesced 32B record load; zero dependent hops ----
            const int  eA = eb + c16;
            const bool vA = eA < e1;
            size_t ri = (size_t)(vA ? eA : e0) * 2;
            uint4 ra = recs[ri];
            uint4 rb = recs[ri + 1];
            pin[0] = __uint_as_float(ra.z); pin[1] = __uint_as_float(ra.w);
            pin[2] = __uint_as_float(rb.x); pin[3] = __uint_as_float(rb.y);
            pin[4] = __uint_as_float(rb.z); pin[5] = __uint_as_float(rb.w);
            // epilogue d/s pairs: 8B loads from the same L1-hot 512B line
#pragma unroll
            for (int i = 0; i < 4; ++i) {
                int ee  = eb + g * 4 + i;
                v_ep[i] = ee < e1;
                uint2 ds = *(const uint2*)&recs[(size_t)(v_ep[i] ? ee : e0) * 2];
                s_ep[i] = (int)ds.y;
                soff[i] = ((int)ds.x - q0) * 129 + c16;
            }
        } else {
            const int  eA = eb + c16;
            const bool vA = eA < e1;
            const int  dA = vA ? dsts[eA] : q0;
            const int  sA = vA ? srcs[eA] : 0;
#pragma unroll
            for (int i = 0; i < 4; ++i) {
                int ee = eb + g * 4 + i;
                v_ep[i] = ee < e1;
                int d   = v_ep[i] ? dsts[ee] : q0;
                s_ep[i] = v_ep[i] ? srcs[ee] : 0;
                soff[i] = (d - q0) * 129 + c16;
            }
            const float* pq = qpos + dA * 3;
            pin[0] = pq[0]; pin[1] = pq[1]; pin[2] = pq[2];
            const float* pl = lpos + sA * 3;
            pin[3] = pl[0]; pin[4] = pl[1]; pin[5] = pl[2];
        }

        if constexpr (SKEL) {
            // ===== MEMORY SKELETON: same memory ops, no math =====
            // sink pin (keeps both rec loads live)
            float psink = pin[0] + pin[1] + pin[2] + pin[3] + pin[4] + pin[5];
            asm volatile("" :: "v"(psink));
            // bulk rndata gather (same 32 loads/lane as real epilogue)
            f32x4 rr[8];
#pragma unroll
            for (int nt = 0; nt < 8; ++nt)
#pragma unroll
                for (int i = 0; i < 4; ++i)
                    rr[nt][i] = rndata[(size_t)s_ep[i] * 128 + nt * 16 + c16];
            // hb DS roundtrip: 16 b16 writes (rr-derived) + 2 b128 reads
#pragma unroll
            for (int nt = 0; nt < 4; ++nt)
#pragma unroll
                for (int i = 0; i < 4; ++i) {
                    const int row  = g * 4 + i;
                    const int colh = nt * 16 + c16;
                    *(_Float16*)(hb + row * 128 + (((colh >> 3) ^ (row & 7)) * 16)
                                 + (colh & 7) * 2) = (_Float16)rr[nt][i];
                }
            const half8 a2 = *(const half8*)(hb + aoff0);
            const half8 a3 = *(const half8*)(hb + aoff1);
            float hsink = (float)a2[0] + (float)a3[7];
            asm volatile("" :: "v"(hsink));
            // sacc atomics: same 32 LDS atomic adds
#pragma unroll
            for (int nt = 0; nt < 8; ++nt)
#pragma unroll
                for (int i = 0; i < 4; ++i)
                    if (v_ep[i]) atomicAdd(&sacc[soff[i] + nt * 16], rr[nt][i]);
            continue;
        }

        // ---- L0: compute A-fragment directly (edge c16, cols g*8 sliced) ----
        float C0[16];
        {
            const float* b0p = b0 + g * 8;
            *(float4*)&C0[0]  = *(const float4*)(b0p);
            *(float4*)&C0[4]  = *(const float4*)(b0p + 4);
            *(float4*)&C0[8]  = *(const float4*)(b0p + 32);
            *(float4*)&C0[12] = *(const float4*)(b0p + 36);
        }
#pragma unroll
        for (int k = 0; k < 6; ++k) {
            const float a  = pin[k];
            const float* w = W0 + k * 64 + g * 8;   // L1-hot (1.5 KB total)
            float wv[16];
            *(float4*)&wv[0]  = *(const float4*)(w);
            *(float4*)&wv[4]  = *(const float4*)(w + 4);
            *(float4*)&wv[8]  = *(const float4*)(w + 32);
            *(float4*)&wv[12] = *(const float4*)(w + 36);
#pragma unroll
            for (int j = 0; j < 16; ++j) C0[j] = fmaf(a, wv[j], C0[j]);
        }
        union { _Float16 h[8]; half8 v; } u0, u1;
#pragma unroll
        for (int j = 0; j < 8; ++j) u0.h[j] = (_Float16)gelu_f(C0[j]);
#pragma unroll
        for (int j = 0; j < 8; ++j) u1.h[j] = (_Float16)gelu_f(C0[8 + j]);
        const half8 a0 = u0.v, a1 = u1.v;   // h0 A-fragments: no LDS round-trip

        // ---- GEMM2 interleaved with h1 transpose (c1 = one transient f32x4) ----
#pragma unroll
        for (int nt = 0; nt < 4; ++nt) {
            const int  nrow = nt * 16 + c16;
            const char* wb  = smemc + nrow * 128;
            half8 bb0 = *(const half8*)(wb + (((0 + g) ^ (nrow & 7)) * 16));
            half8 bb1 = *(const half8*)(wb + (((4 + g) ^ (nrow & 7)) * 16));
            f32x4 acc = {b1v[nt], b1v[nt], b1v[nt], b1v[nt]};
            acc = __builtin_amdgcn_mfma_f32_16x16x32_f16(a0, bb0, acc, 0, 0, 0);
            acc = __builtin_amdgcn_mfma_f32_16x16x32_f16(a1, bb1, acc, 0, 0, 0);
#pragma unroll
            for (int i = 0; i < 4; ++i) {
                const int row  = g * 4 + i;
                const int colh = nt * 16 + c16;
                *(_Float16*)(hb + row * 128 + (((colh >> 3) ^ (row & 7)) * 16)
                             + (colh & 7) * 2) = (_Float16)gelu_f(acc[i]);
            }
        }
        // in-order DS per wave: reads below see the 16 writes above
        const half8 a2 = *(const half8*)(hb + aoff0);
        const half8 a3 = *(const half8*)(hb + aoff1);

        // ---- GEMM3 + epilogue, 2-deep rolling rndata buffer ----
        f32x4 rAv, rBv;
#pragma unroll
        for (int i = 0; i < 4; ++i)
            rAv[i] = rndata[(size_t)s_ep[i] * 128 + c16];      // nt=0 column
#pragma unroll
        for (int nt = 0; nt < 8; ++nt) {
            if (nt < 7) {        // issue nt+1 loads (hide under MFMAs)
                if (nt & 1) {
#pragma unroll
                    for (int i = 0; i < 4; ++i)
                        rAv[i] = rndata[(size_t)s_ep[i] * 128 + (nt + 1) * 16 + c16];
                } else {
#pragma unroll
                    for (int i = 0; i < 4; ++i)
                        rBv[i] = rndata[(size_t)s_ep[i] * 128 + (nt + 1) * 16 + c16];
                }
            }
            const int  nrow = nt * 16 + c16;
            const char* wb  = smemc + 8192 + nrow * 128;
            half8 bb0 = *(const half8*)(wb + (((0 + g) ^ (nrow & 7)) * 16));
            half8 bb1 = *(const half8*)(wb + (((4 + g) ^ (nrow & 7)) * 16));
            f32x4 acc = {b2v[nt], b2v[nt], b2v[nt], b2v[nt]};
            acc = __builtin_amdgcn_mfma_f32_16x16x32_f16(a2, bb0, acc, 0, 0, 0);
            acc = __builtin_amdgcn_mfma_f32_16x16x32_f16(a3, bb1, acc, 0, 0, 0);
#pragma unroll
            for (int i = 0; i < 4; ++i) {
                float rc = (nt & 1) ? rBv[i] : rAv[i];
                if (v_ep[i]) atomicAdd(&sacc[soff[i] + nt * 16], acc[i] * rc);
            }
        }
    }
    __syncthreads();  // all waves' ds_adds visible

    if (!FUSED_PROJ) {
        for (int idx = tid; idx < QB * 128; idx += BLOCK) {
            int ql = idx >> 7, c = idx & 127;
            int q  = q0 + ql;
            if (q < qend) {
                float deg = (float)(start[q + 1] - start[q]);
                agg[(size_t)q * 128 + c] = sacc[ql * 129 + c] / fmaxf(deg, 1.f);
            }
        }
    } else {
        if (tid < QB) {
            int q = q0 + tid;
            if (q < nq) {
                float deg = (float)(start[q + 1] - start[q]);
                float inv = 1.0f / fmaxf(deg, 1.f);
                const float* aq = &sacc[tid * 129];
                float o0 = pb1[0], o1 = pb1[1], o2 = pb1[2], o3 = pb1[3];
#pragma unroll 1
                for (int jj = 0; jj < 256; jj += 8) {
                    float acc[8];
#pragma unroll
                    for (int u = 0; u < 8; ++u) acc[u] = pb0[jj + u];
#pragma unroll
                    for (int i = 0; i < 128; ++i) {
                        float av = aq[i] * inv;
#pragma unroll
                        for (int u = 0; u < 8; ++u)
                            acc[u] = fmaf(av, P0[i * 256 + jj + u], acc[u]);
                    }
#pragma unroll
                    for (int u = 0; u < 8; ++u) {
                        float h = gelu_f(acc[u]);
                        o0 = fmaf(h, P1[(jj + u) * 4 + 0], o0);
                        o1 = fmaf(h, P1[(jj + u) * 4 + 1], o1);
                        o2 = fmaf(h, P1[(jj + u) * 4 + 2], o2);
                        o3 = fmaf(h, P1[(jj + u) * 4 + 3], o3);
                    }
                }
                float4* o4 = (float4*)(out + (size_t)q * 4);
                *o4 = make_float4(o0, o1, o2, o3);
            }
        }
    }
}

// ---------- projection: plain r7/r9 kernel (proven ~270 us) ----------

__global__ __launch_bounds__(256) void proj_kernel(
    const float* __restrict__ agg,      // [NQ,128] mean
    const float* __restrict__ P0, const float* __restrict__ pb0,
    const float* __restrict__ P1, const float* __restrict__ pb1,
    float* __restrict__ out, int nq)
{
    int q = blockIdx.x * blockDim.x + threadIdx.x;
    if (q >= nq) return;

    float a[128];
    const float4* ag4 = (const float4*)(agg + (size_t)q * 128);
#pragma unroll
    for (int i = 0; i < 32; ++i) {
        float4 v = ag4[i];
        a[4 * i + 0] = v.x; a[4 * i + 1] = v.y;
        a[4 * i + 2] = v.z; a[4 * i + 3] = v.w;
    }

    float o0 = pb1[0], o1 = pb1[1], o2 = pb1[2], o3 = pb1[3];
#pragma unroll 1
    for (int jj = 0; jj < 256; jj += 8) {
        float acc[8];
#pragma unroll
        for (int u = 0; u < 8; ++u) acc[u] = pb0[jj + u];
#pragma unroll
        for (int i = 0; i < 128; ++i) {
            float av = a[i];
#pragma unroll
            for (int u = 0; u < 8; ++u)
                acc[u] = fmaf(av, P0[i * 256 + jj + u], acc[u]);
        }
#pragma unroll
        for (int u = 0; u < 8; ++u) {
            float h = gelu_f(acc[u]);
            o0 = fmaf(h, P1[(jj + u) * 4 + 0], o0);
            o1 = fmaf(h, P1[(jj + u) * 4 + 1], o1);
            o2 = fmaf(h, P1[(jj + u) * 4 + 2], o2);
            o3 = fmaf(h, P1[(jj + u) * 4 + 3], o3);
        }
    }
    float4* o4 = (float4*)(out + (size_t)q * 4);
    *o4 = make_float4(o0, o1, o2, o3);
}

extern "C" void kernel_launch(void* const* d_in, const int* in_sizes, int n_in,
                              void* d_out, int out_size, void* d_ws, size_t ws_size,
                              hipStream_t stream)
{
    const float* rndata = (const float*)d_in[0];
    const float* qpos   = (const float*)d_in[1];
    const float* lpos   = (const float*)d_in[2];
    const int*   dst    = (const int*)d_in[3];
    const int*   src    = (const int*)d_in[4];
    const float* W0  = (const float*)d_in[5];
    const float* b0  = (const float*)d_in[6];
    const float* W1  = (const float*)d_in[7];
    const float* b1  = (const float*)d_in[8];
    const float* W2  = (const float*)d_in[9];
    const float* b2  = (const float*)d_in[10];
    const float* P0  = (const float*)d_in[11];
    const float* pb0 = (const float*)d_in[12];
    const float* P1  = (const float*)d_in[13];
    const float* pb1 = (const float*)d_in[14];

    int nq = in_sizes[1] / 3;
    int E  = in_sizes[3];

    size_t agg_bytes  = (size_t)nq * 128 * sizeof(float);
    size_t histpad    = ((size_t)nq * sizeof(int) + 15) & ~(size_t)15;
    size_t startpad   = ((size_t)(nq + 1) * sizeof(int) + 15) & ~(size_t)15;
    size_t epad       = ((size_t)E * sizeof(int) + 15) & ~(size_t)15;
    size_t recs_bytes = (size_t)E * 32;
    size_t fixed      = 2 * histpad + startpad;

    size_t need_rec = agg_bytes + fixed + recs_bytes + 24576;   // rec path + agg
    size_t need_old = agg_bytes + fixed + 2 * epad + 24576;     // old path + agg

    bool use_rec = ws_size >= need_rec;
    bool path_a  = use_rec || (ws_size >= need_old);

    size_t off = path_a ? agg_bytes : 0;
    auto alloc = [&](size_t bytes) {
        void* p = (char*)d_ws + off;
        off += (bytes + 15) & ~(size_t)15;
        return p;
    };
    float* agg   = (float*)d_ws;  // path A only
    int* hist    = (int*)alloc((size_t)nq * sizeof(int));
    int* cursor  = (int*)alloc((size_t)nq * sizeof(int));
    int* start   = (int*)alloc((size_t)(nq + 1) * sizeof(int));
    uint4* recs  = nullptr;
    int* dsts    = nullptr;
    int* srcs    = nullptr;
    if (use_rec) {
        recs = (uint4*)alloc(recs_bytes);
    } else {
        dsts = (int*)alloc((size_t)E * sizeof(int));
        srcs = (int*)alloc((size_t)E * sizeof(int));
    }
    uint4* wimg  = (uint4*)alloc(24576);

    hipMemsetAsync(hist, 0, 2 * histpad, stream);

    wprep_kernel<<<1, 256, 0, stream>>>(W1, W2, (char*)wimg);
    hist_kernel<<<(E + 255) / 256, 256, 0, stream>>>(dst, hist, E);
    scan_kernel<<<1, 1024, 0, stream>>>(hist, start, nq);
    if (use_rec) {
        scatter_rec_kernel<<<(E + 255) / 256, 256, 0, stream>>>(
            dst, src, start, cursor, qpos, lpos, recs, E);
    } else {
        scatter_kernel<<<(E + 255) / 256, 256, 0, stream>>>(
            dst, src, start, cursor, dsts, srcs, E);
    }

    constexpr int    QB   = 12;
    constexpr size_t SMEM = 32768 + (size_t)QB * 129 * 4;  // 38,960 B -> 4 blocks/CU
    int nb = (nq + QB - 1) / QB;

    if (path_a) {
        if (use_rec) {
            // DIAGNOSTIC: memory skeleton first (garbage agg, fully
            // overwritten by the real kernel below).
            fused_kernel<QB, false, true, true><<<nb, BLOCK, SMEM, stream>>>(
                rndata, qpos, lpos, recs, dsts, srcs, start,
                W0, b0, b1, b2, wimg, P0, pb0, P1, pb1, agg, nullptr, nq);
            fused_kernel<QB, false, true, false><<<nb, BLOCK, SMEM, stream>>>(
                rndata, qpos, lpos, recs, dsts, srcs, start,
                W0, b0, b1, b2, wimg, P0, pb0, P1, pb1, agg, nullptr, nq);
        } else {
            fused_kernel<QB, false, false, false><<<nb, BLOCK, SMEM, stream>>>(
                rndata, qpos, lpos, recs, dsts, srcs, start,
                W0, b0, b1, b2, wimg, P0, pb0, P1, pb1, agg, nullptr, nq);
        }
        proj_kernel<<<(nq + 255) / 256, 256, 0, stream>>>(
            agg, P0, pb0, P1, pb1, (float*)d_out, nq);
    } else {
        fused_kernel<QB, true, false, false><<<nb, BLOCK, SMEM, stream>>>(
            rndata, qpos, lpos, recs, dsts, srcs, start,
            W0, b0, b1, b2, wimg, P0, pb0, P1, pb1, nullptr, (float*)d_out, nq);
    }
}

// Round 21
// 1161.852 us; speedup vs baseline: 1.5799x; 1.5799x over previous
//
#include <hip/hip_runtime.h>

// GNODecoder round 31 (resubmit; never ran -- broker timeout).
// r30 ablation: T_skel = 1835.6-1167.7 = ~668us (<752, not in top-5) ->
// memory ops alone are ~88% of the fused kernel's 755us; math is free.
// Dominant term by arithmetic: rndata gather -- 32 instrs/tile x 4 random
// 64B segments in an 8MB table vs 4MB L2/XCD -> ~50% miss to L3 (500-900cy)
// at ~8 waves/CU. r31 = r28 structure (proven 763us, no spills) + rprep
// kernel converting rndata to a 4MB f16 table: halves gather bytes AND
// makes the table L2-resident -> gather latency ~200-300cy.
// Precision: error enters as k*dr, dr~3e-4 RMS, sign-averaged over deg~10
// and the 128-wide proj dot -> added absmax ~few e-6 (current 7.6e-6 passes
// with margin). Predicted: fused 755 -> 550-650us; absmax <=2e-5; VGPR<=124;
// WRITE ~50MB. Null <=5% falsifies gather dominance -> next: split skeleton.

#define BLOCK 256

typedef _Float16 half8 __attribute__((ext_vector_type(8)));
typedef float f32x4 __attribute__((ext_vector_type(4)));

// LDS byte layout (fused kernel):
//   [0,     8192)  W1T : [64 n][64 k] f16, chunk ^= (n&7)
//   [8192, 24576)  W2T : [128 n][64 k] f16, same swizzle
//   [24576, 32768) hbuf: per-wave 2 KB, [16 rows][8 chunks of 16B], chunk^=(row&7)
//   [32768, ... )  sacc: [QB][129] f32

__device__ __forceinline__ float gelu_f(float x) {
    // jax.nn.gelu default (approximate=True, tanh form)
    float x3 = x * x * x;
    float t  = 0.7978845608028654f * fmaf(0.044715f, x3, x);
    float e  = __expf(2.0f * t);
    float r  = __builtin_amdgcn_rcpf(e + 1.0f);
    return 0.5f * x * (1.0f + (1.0f - 2.0f * r));
}

// ---------- sort machinery (proven) ----------

__global__ void hist_kernel(const int* __restrict__ dst, int* __restrict__ hist, int E) {
    int e = blockIdx.x * blockDim.x + threadIdx.x;
    if (e < E) atomicAdd(&hist[dst[e]], 1);
}

__global__ __launch_bounds__(1024) void scan_kernel(const int* __restrict__ hist,
                                                    int* __restrict__ start, int n) {
    __shared__ int wsum[16];
    __shared__ int woff[16];
    int tid = threadIdx.x;
    int lane = tid & 63, wid = tid >> 6;
    int carry = 0;  // meaningful on tid 0 only
    for (int base = 0; base < n; base += 1024) {
        int i = base + tid;
        int v = (i < n) ? hist[i] : 0;
        int incl = v;
#pragma unroll
        for (int off = 1; off < 64; off <<= 1) {
            int t = __shfl_up(incl, off, 64);
            if (lane >= off) incl += t;
        }
        if (lane == 63) wsum[wid] = incl;
        __syncthreads();
        if (tid == 0) {
            int acc = carry;
#pragma unroll
            for (int w = 0; w < 16; ++w) { woff[w] = acc; acc += wsum[w]; }
            carry = acc;
        }
        __syncthreads();
        if (i < n) start[i] = woff[wid] + incl - v;
        __syncthreads();
    }
    if (threadIdx.x == 0) start[n] = carry;
}

// old path: positions only
__global__ void scatter_kernel(const int* __restrict__ dst, const int* __restrict__ src,
                               const int* __restrict__ start, int* __restrict__ cursor,
                               int* __restrict__ dsts, int* __restrict__ srcs, int E) {
    int e = blockIdx.x * blockDim.x + threadIdx.x;
    if (e >= E) return;
    int d = dst[e];
    int pos = start[d] + atomicAdd(&cursor[d], 1);
    dsts[pos] = d;
    srcs[pos] = src[e];
}

// rec path: 32B record {d, s, qpos[d].xyz, lpos[s].xyz}
__global__ void scatter_rec_kernel(const int* __restrict__ dst, const int* __restrict__ src,
                                   const int* __restrict__ start, int* __restrict__ cursor,
                                   const float* __restrict__ qpos,
                                   const float* __restrict__ lpos,
                                   uint4* __restrict__ recs, int E) {
    int e = blockIdx.x * blockDim.x + threadIdx.x;
    if (e >= E) return;
    int d = dst[e], s = src[e];
    int pos = start[d] + atomicAdd(&cursor[d], 1);
    const float* pq = qpos + (size_t)d * 3;
    const float* pl = lpos + (size_t)s * 3;
    uint4 u0, u1;
    u0.x = (unsigned)d;            u0.y = (unsigned)s;
    u0.z = __float_as_uint(pq[0]); u0.w = __float_as_uint(pq[1]);
    u1.x = __float_as_uint(pq[2]); u1.y = __float_as_uint(pl[0]);
    u1.z = __float_as_uint(pl[1]); u1.w = __float_as_uint(pl[2]);
    size_t ri = (size_t)pos * 2;
    recs[ri] = u0; recs[ri + 1] = u1;
}

// ---------- rndata prep: f32 -> f16 table (4 MB, L2-resident/XCD) ----------

__global__ void rprep_kernel(const float* __restrict__ rnd,
                             _Float16* __restrict__ rh, int n) {
    int i = blockIdx.x * blockDim.x + threadIdx.x;
    if (i < n) rh[i] = (_Float16)rnd[i];
}

// ---------- weight prep: f16, transposed [n][k], XOR-swizzled image ----------
// img bytes: W1T at [0,8192), W2T at [8192,24576).
// element (n,k): byte = base + n*128 + (((k>>3) ^ (n&7))*16) + (k&7)*2

__global__ void wprep_kernel(const float* __restrict__ W1,
                             const float* __restrict__ W2,
                             char* __restrict__ img) {
    union { _Float16 h[8]; uint4 u; } cv;
    for (int task = threadIdx.x; task < 1536; task += 256) {
        bool isW2 = task >= 512;
        int id = isW2 ? task - 512 : task;
        int n = id >> 3, kc = id & 7;
        const float* W = isW2 ? W2 : W1;
        int N = isW2 ? 128 : 64;
#pragma unroll
        for (int j = 0; j < 8; ++j) cv.h[j] = (_Float16)W[(kc * 8 + j) * N + n];
        *(uint4*)(img + (isW2 ? 8192 : 0) + n * 128 + ((kc ^ (n & 7)) * 16)) = cv.u;
    }
}

// ---------- fused: wave-private 16-edge tiles, zero barriers in loop ----------

template <int QB, bool FUSED_PROJ, bool RECS>
__global__ __launch_bounds__(BLOCK, 2) void fused_kernel(
    const _Float16* __restrict__ rh,    // [NL,128] f16 table
    const float* __restrict__ qpos,     // [NQ,3]
    const float* __restrict__ lpos,     // [NL,3]
    const uint4* __restrict__ recs,     // [E*2] edge records (RECS path)
    const int*   __restrict__ dsts,     // [E] sorted by dst (old path)
    const int*   __restrict__ srcs,     // [E] (old path)
    const int*   __restrict__ start,    // [NQ+1]
    const float* __restrict__ W0, const float* __restrict__ b0,
    const float* __restrict__ b1, const float* __restrict__ b2,
    const uint4* __restrict__ wimg,     // 24576 B packed W1T/W2T image
    const float* __restrict__ P0, const float* __restrict__ pb0,
    const float* __restrict__ P1, const float* __restrict__ pb1,
    float* __restrict__ agg,            // [NQ,128] mean (path A)
    float* __restrict__ out,            // [NQ,4]   (FUSED_PROJ)
    int nq)
{
    extern __shared__ char smemc[];
    float* sacc = (float*)(smemc + 32768);
    const int tid = threadIdx.x;

    // stage weight image -> LDS [0, 24576)
    {
        uint4* wdst = (uint4*)smemc;
        for (int i = tid; i < 1536; i += BLOCK) wdst[i] = wimg[i];
    }
    for (int i = tid; i < QB * 129; i += BLOCK) sacc[i] = 0.f;

    const int q0   = blockIdx.x * QB;
    const int qend = min(q0 + QB, nq);
    const int e0 = start[q0], e1 = start[qend];
    const int ntl = (e1 - e0 + 15) >> 4;   // 16-edge tiles

    const int m   = tid & 63;
    const int wid = tid >> 6;
    const int c16 = m & 15;
    const int g   = m >> 4;                // 0..3 = k-group

    char* hb = smemc + 24576 + wid * 2048; // wave-private h1 buffer
    const int aoff0 = c16 * 128 + (((0 + g) ^ (c16 & 7)) * 16);  // A frag k=g*8..
    const int aoff1 = c16 * 128 + (((4 + g) ^ (c16 & 7)) * 16);  // A frag k=32+g*8..

    // per-lane bias slices (hoisted; 12 loop-carried regs)
    float b1v[4], b2v[8];
#pragma unroll
    for (int nt = 0; nt < 4; ++nt) b1v[nt] = b1[nt * 16 + c16];
#pragma unroll
    for (int nt = 0; nt < 8; ++nt) b2v[nt] = b2[nt * 16 + c16];

    __syncthreads();  // weights staged + sacc zeroed (only barrier before tail)

    for (int t = wid; t < ntl; t += 4) {
        const int eb = e0 + (t << 4);

        float pin[6];
        int s_ep[4], soff[4];
        bool v_ep[4];

        if constexpr (RECS) {
            // ---- ONE coalesced 32B record load; zero dependent hops ----
            const int  eA = eb + c16;
            const bool vA = eA < e1;
            size_t ri = (size_t)(vA ? eA : e0) * 2;
            uint4 ra = recs[ri];
            uint4 rb = recs[ri + 1];
            pin[0] = __uint_as_float(ra.z); pin[1] = __uint_as_float(ra.w);
            pin[2] = __uint_as_float(rb.x); pin[3] = __uint_as_float(rb.y);
            pin[4] = __uint_as_float(rb.z); pin[5] = __uint_as_float(rb.w);
            // epilogue d/s pairs: 8B loads from the same L1-hot 512B line
#pragma unroll
            for (int i = 0; i < 4; ++i) {
                int ee  = eb + g * 4 + i;
                v_ep[i] = ee < e1;
                uint2 ds = *(const uint2*)&recs[(size_t)(v_ep[i] ? ee : e0) * 2];
                s_ep[i] = (int)ds.y;
                soff[i] = ((int)ds.x - q0) * 129 + c16;
            }
        } else {
            // ---- old r26 path: index gather + dependent pos gather ----
            const int  eA = eb + c16;
            const bool vA = eA < e1;
            const int  dA = vA ? dsts[eA] : q0;
            const int  sA = vA ? srcs[eA] : 0;
#pragma unroll
            for (int i = 0; i < 4; ++i) {
                int ee = eb + g * 4 + i;
                v_ep[i] = ee < e1;
                int d   = v_ep[i] ? dsts[ee] : q0;
                s_ep[i] = v_ep[i] ? srcs[ee] : 0;
                soff[i] = (d - q0) * 129 + c16;
            }
            const float* pq = qpos + dA * 3;
            pin[0] = pq[0]; pin[1] = pq[1]; pin[2] = pq[2];
            const float* pl = lpos + sA * 3;
            pin[3] = pl[0]; pin[4] = pl[1]; pin[5] = pl[2];
        }

        // ---- L0: compute A-fragment directly (edge c16, cols g*8 sliced) ----
        float C0[16];
        {
            const float* b0p = b0 + g * 8;
            *(float4*)&C0[0]  = *(const float4*)(b0p);
            *(float4*)&C0[4]  = *(const float4*)(b0p + 4);
            *(float4*)&C0[8]  = *(const float4*)(b0p + 32);
            *(float4*)&C0[12] = *(const float4*)(b0p + 36);
        }
#pragma unroll
        for (int k = 0; k < 6; ++k) {
            const float a  = pin[k];
            const float* w = W0 + k * 64 + g * 8;   // L1-hot (1.5 KB total)
            float wv[16];
            *(float4*)&wv[0]  = *(const float4*)(w);
            *(float4*)&wv[4]  = *(const float4*)(w + 4);
            *(float4*)&wv[8]  = *(const float4*)(w + 32);
            *(float4*)&wv[12] = *(const float4*)(w + 36);
#pragma unroll
            for (int j = 0; j < 16; ++j) C0[j] = fmaf(a, wv[j], C0[j]);
        }
        union { _Float16 h[8]; half8 v; } u0, u1;
#pragma unroll
        for (int j = 0; j < 8; ++j) u0.h[j] = (_Float16)gelu_f(C0[j]);
#pragma unroll
        for (int j = 0; j < 8; ++j) u1.h[j] = (_Float16)gelu_f(C0[8 + j]);
        const half8 a0 = u0.v, a1 = u1.v;   // h0 A-fragments: no LDS round-trip

        // ---- GEMM2 interleaved with h1 transpose (c1 = one transient f32x4) ----
#pragma unroll
        for (int nt = 0; nt < 4; ++nt) {
            const int  nrow = nt * 16 + c16;
            const char* wb  = smemc + nrow * 128;
            half8 bb0 = *(const half8*)(wb + (((0 + g) ^ (nrow & 7)) * 16));
            half8 bb1 = *(const half8*)(wb + (((4 + g) ^ (nrow & 7)) * 16));
            f32x4 acc = {b1v[nt], b1v[nt], b1v[nt], b1v[nt]};
            acc = __builtin_amdgcn_mfma_f32_16x16x32_f16(a0, bb0, acc, 0, 0, 0);
            acc = __builtin_amdgcn_mfma_f32_16x16x32_f16(a1, bb1, acc, 0, 0, 0);
#pragma unroll
            for (int i = 0; i < 4; ++i) {
                const int row  = g * 4 + i;
                const int colh = nt * 16 + c16;
                *(_Float16*)(hb + row * 128 + (((colh >> 3) ^ (row & 7)) * 16)
                             + (colh & 7) * 2) = (_Float16)gelu_f(acc[i]);
            }
        }
        // in-order DS per wave: reads below see the 16 writes above
        const half8 a2 = *(const half8*)(hb + aoff0);
        const half8 a3 = *(const half8*)(hb + aoff1);

        // ---- GEMM3 + epilogue, 2-deep rolling f16 rndata buffer ----
        f32x4 rAv, rBv;
#pragma unroll
        for (int i = 0; i < 4; ++i)
            rAv[i] = (float)rh[(size_t)s_ep[i] * 128 + c16];   // nt=0 column
#pragma unroll
        for (int nt = 0; nt < 8; ++nt) {
            if (nt < 7) {        // issue nt+1 loads (hide under MFMAs)
                if (nt & 1) {
#pragma unroll
                    for (int i = 0; i < 4; ++i)
                        rAv[i] = (float)rh[(size_t)s_ep[i] * 128 + (nt + 1) * 16 + c16];
                } else {
#pragma unroll
                    for (int i = 0; i < 4; ++i)
                        rBv[i] = (float)rh[(size_t)s_ep[i] * 128 + (nt + 1) * 16 + c16];
                }
            }
            const int  nrow = nt * 16 + c16;
            const char* wb  = smemc + 8192 + nrow * 128;
            half8 bb0 = *(const half8*)(wb + (((0 + g) ^ (nrow & 7)) * 16));
            half8 bb1 = *(const half8*)(wb + (((4 + g) ^ (nrow & 7)) * 16));
            f32x4 acc = {b2v[nt], b2v[nt], b2v[nt], b2v[nt]};
            acc = __builtin_amdgcn_mfma_f32_16x16x32_f16(a2, bb0, acc, 0, 0, 0);
            acc = __builtin_amdgcn_mfma_f32_16x16x32_f16(a3, bb1, acc, 0, 0, 0);
#pragma unroll
            for (int i = 0; i < 4; ++i) {
                float rc = (nt & 1) ? rBv[i] : rAv[i];
                if (v_ep[i]) atomicAdd(&sacc[soff[i] + nt * 16], acc[i] * rc);
            }
        }
    }
    __syncthreads();  // all waves' ds_adds visible

    if (!FUSED_PROJ) {
        for (int idx = tid; idx < QB * 128; idx += BLOCK) {
            int ql = idx >> 7, c = idx & 127;
            int q  = q0 + ql;
            if (q < qend) {
                float deg = (float)(start[q + 1] - start[q]);
                agg[(size_t)q * 128 + c] = sacc[ql * 129 + c] / fmaxf(deg, 1.f);
            }
        }
    } else {
        if (tid < QB) {
            int q = q0 + tid;
            if (q < nq) {
                float deg = (float)(start[q + 1] - start[q]);
                float inv = 1.0f / fmaxf(deg, 1.f);
                const float* aq = &sacc[tid * 129];
                float o0 = pb1[0], o1 = pb1[1], o2 = pb1[2], o3 = pb1[3];
#pragma unroll 1
                for (int jj = 0; jj < 256; jj += 8) {
                    float acc[8];
#pragma unroll
                    for (int u = 0; u < 8; ++u) acc[u] = pb0[jj + u];
#pragma unroll
                    for (int i = 0; i < 128; ++i) {
                        float av = aq[i] * inv;
#pragma unroll
                        for (int u = 0; u < 8; ++u)
                            acc[u] = fmaf(av, P0[i * 256 + jj + u], acc[u]);
                    }
#pragma unroll
                    for (int u = 0; u < 8; ++u) {
                        float h = gelu_f(acc[u]);
                        o0 = fmaf(h, P1[(jj + u) * 4 + 0], o0);
                        o1 = fmaf(h, P1[(jj + u) * 4 + 1], o1);
                        o2 = fmaf(h, P1[(jj + u) * 4 + 2], o2);
                        o3 = fmaf(h, P1[(jj + u) * 4 + 3], o3);
                    }
                }
                float4* o4 = (float4*)(out + (size_t)q * 4);
                *o4 = make_float4(o0, o1, o2, o3);
            }
        }
    }
}

// ---------- projection: plain r7/r9 kernel (proven ~270 us) ----------

__global__ __launch_bounds__(256) void proj_kernel(
    const float* __restrict__ agg,      // [NQ,128] mean
    const float* __restrict__ P0, const float* __restrict__ pb0,
    const float* __restrict__ P1, const float* __restrict__ pb1,
    float* __restrict__ out, int nq)
{
    int q = blockIdx.x * blockDim.x + threadIdx.x;
    if (q >= nq) return;

    float a[128];
    const float4* ag4 = (const float4*)(agg + (size_t)q * 128);
#pragma unroll
    for (int i = 0; i < 32; ++i) {
        float4 v = ag4[i];
        a[4 * i + 0] = v.x; a[4 * i + 1] = v.y;
        a[4 * i + 2] = v.z; a[4 * i + 3] = v.w;
    }

    float o0 = pb1[0], o1 = pb1[1], o2 = pb1[2], o3 = pb1[3];
#pragma unroll 1
    for (int jj = 0; jj < 256; jj += 8) {
        float acc[8];
#pragma unroll
        for (int u = 0; u < 8; ++u) acc[u] = pb0[jj + u];
#pragma unroll
        for (int i = 0; i < 128; ++i) {
            float av = a[i];
#pragma unroll
            for (int u = 0; u < 8; ++u)
                acc[u] = fmaf(av, P0[i * 256 + jj + u], acc[u]);
        }
#pragma unroll
        for (int u = 0; u < 8; ++u) {
            float h = gelu_f(acc[u]);
            o0 = fmaf(h, P1[(jj + u) * 4 + 0], o0);
            o1 = fmaf(h, P1[(jj + u) * 4 + 1], o1);
            o2 = fmaf(h, P1[(jj + u) * 4 + 2], o2);
            o3 = fmaf(h, P1[(jj + u) * 4 + 3], o3);
        }
    }
    float4* o4 = (float4*)(out + (size_t)q * 4);
    *o4 = make_float4(o0, o1, o2, o3);
}

extern "C" void kernel_launch(void* const* d_in, const int* in_sizes, int n_in,
                              void* d_out, int out_size, void* d_ws, size_t ws_size,
                              hipStream_t stream)
{
    const float* rndata = (const float*)d_in[0];
    const float* qpos   = (const float*)d_in[1];
    const float* lpos   = (const float*)d_in[2];
    const int*   dst    = (const int*)d_in[3];
    const int*   src    = (const int*)d_in[4];
    const float* W0  = (const float*)d_in[5];
    const float* b0  = (const float*)d_in[6];
    const float* W1  = (const float*)d_in[7];
    const float* b1  = (const float*)d_in[8];
    const float* W2  = (const float*)d_in[9];
    const float* b2  = (const float*)d_in[10];
    const float* P0  = (const float*)d_in[11];
    const float* pb0 = (const float*)d_in[12];
    const float* P1  = (const float*)d_in[13];
    const float* pb1 = (const float*)d_in[14];

    int nq  = in_sizes[1] / 3;
    int E   = in_sizes[3];
    int nrl = in_sizes[0];          // NL*128 elements

    size_t agg_bytes  = (size_t)nq * 128 * sizeof(float);
    size_t histpad    = ((size_t)nq * sizeof(int) + 15) & ~(size_t)15;
    size_t startpad   = ((size_t)(nq + 1) * sizeof(int) + 15) & ~(size_t)15;
    size_t epad       = ((size_t)E * sizeof(int) + 15) & ~(size_t)15;
    size_t recs_bytes = (size_t)E * 32;
    size_t rh_bytes   = ((size_t)nrl * 2 + 15) & ~(size_t)15;
    size_t fixed      = 2 * histpad + startpad + rh_bytes + 24576;

    size_t need_rec = agg_bytes + fixed + recs_bytes;   // rec path + agg
    size_t need_old = agg_bytes + fixed + 2 * epad;     // old path + agg

    bool use_rec = ws_size >= need_rec;
    bool path_a  = use_rec || (ws_size >= need_old);

    size_t off = path_a ? agg_bytes : 0;
    auto alloc = [&](size_t bytes) {
        void* p = (char*)d_ws + off;
        off += (bytes + 15) & ~(size_t)15;
        return p;
    };
    float* agg     = (float*)d_ws;  // path A only
    int* hist      = (int*)alloc((size_t)nq * sizeof(int));
    int* cursor    = (int*)alloc((size_t)nq * sizeof(int));
    int* start     = (int*)alloc((size_t)(nq + 1) * sizeof(int));
    _Float16* rh   = (_Float16*)alloc(rh_bytes);
    uint4* recs  = nullptr;
    int* dsts    = nullptr;
    int* srcs    = nullptr;
    if (use_rec) {
        recs = (uint4*)alloc(recs_bytes);
    } else {
        dsts = (int*)alloc((size_t)E * sizeof(int));
        srcs = (int*)alloc((size_t)E * sizeof(int));
    }
    uint4* wimg  = (uint4*)alloc(24576);

    hipMemsetAsync(hist, 0, 2 * histpad, stream);

    wprep_kernel<<<1, 256, 0, stream>>>(W1, W2, (char*)wimg);
    rprep_kernel<<<(nrl + 255) / 256, 256, 0, stream>>>(rndata, rh, nrl);
    hist_kernel<<<(E + 255) / 256, 256, 0, stream>>>(dst, hist, E);
    scan_kernel<<<1, 1024, 0, stream>>>(hist, start, nq);
    if (use_rec) {
        scatter_rec_kernel<<<(E + 255) / 256, 256, 0, stream>>>(
            dst, src, start, cursor, qpos, lpos, recs, E);
    } else {
        scatter_kernel<<<(E + 255) / 256, 256, 0, stream>>>(
            dst, src, start, cursor, dsts, srcs, E);
    }

    constexpr int    QB   = 12;
    constexpr size_t SMEM = 32768 + (size_t)QB * 129 * 4;  // 38,960 B -> 4 blocks/CU
    int nb = (nq + QB - 1) / QB;

    if (path_a) {
        if (use_rec) {
            fused_kernel<QB, false, true><<<nb, BLOCK, SMEM, stream>>>(
                rh, qpos, lpos, recs, dsts, srcs, start,
                W0, b0, b1, b2, wimg, P0, pb0, P1, pb1, agg, nullptr, nq);
        } else {
            fused_kernel<QB, false, false><<<nb, BLOCK, SMEM, stream>>>(
                rh, qpos, lpos, recs, dsts, srcs, start,
                W0, b0, b1, b2, wimg, P0, pb0, P1, pb1, agg, nullptr, nq);
        }
        proj_kernel<<<(nq + 255) / 256, 256, 0, stream>>>(
            agg, P0, pb0, P1, pb1, (float*)d_out, nq);
    } else {
        fused_kernel<QB, true, false><<<nb, BLOCK, SMEM, stream>>>(
            rh, qpos, lpos, recs, dsts, srcs, start,
            W0, b0, b1, b2, wimg, P0, pb0, P1, pb1, nullptr, (float*)d_out, nq);
    }
}